// Round 6
// baseline (78.764 us; speedup 1.0000x reference)
//
#include <hip/hip_runtime.h>

// out (224,2,257,600) f32 = flat 17,270,400 float4. plane pl = idx/38550,
// pl = b*56 + 2*p + s; src channel from triu_indices(8,k=1) pair table.
__device__ __constant__ int c_ch[56] = {
    0,1, 0,2, 0,3, 0,4, 0,5, 0,6, 0,7,
    1,2, 1,3, 1,4, 1,5, 1,6, 1,7,
    2,3, 2,4, 2,5, 2,6, 2,7,
    3,4, 3,5, 3,6, 3,7,
    4,5, 4,6, 4,7,
    5,6, 5,7,
    6,7
};

typedef float f32x4 __attribute__((ext_vector_type(4)));

#define PLANE4 38550u            // 257*600/4 float4 per plane
#define TOTAL4 17270400u         // 448 * PLANE4
#define EPT    8                 // float4 per thread
#define CHUNK  (256 * EPT)       // 2048 float4 = 32 KB per block

__global__ void gather_pairs_kernel(const f32x4* __restrict__ in,
                                    f32x4* __restrict__ out) {
    unsigned base = blockIdx.x * CHUNK + threadIdx.x;   // lane-contiguous

    unsigned idx[EPT];
    f32x4    v[EPT];
    bool     ok[EPT];

    // Issue all loads first (8-deep MLP), stores after.
#pragma unroll
    for (int k = 0; k < EPT; ++k) {
        unsigned i = base + k * 256;
        idx[k] = i;
        ok[k]  = i < TOTAL4;
        if (ok[k]) {
            unsigned pl  = i / PLANE4;            // magic-mul
            unsigned r   = i - pl * PLANE4;
            unsigned b   = pl / 56u;              // magic-mul
            unsigned rem = pl - b * 56u;
            unsigned ch  = (unsigned)c_ch[rem];
            v[k] = in[(size_t)((b << 3) + ch) * PLANE4 + r];
        }
    }
#pragma unroll
    for (int k = 0; k < EPT; ++k)
        if (ok[k]) __builtin_nontemporal_store(v[k], &out[idx[k]]);
}

extern "C" void kernel_launch(void* const* d_in, const int* in_sizes, int n_in,
                              void* d_out, int out_size, void* d_ws, size_t ws_size,
                              hipStream_t stream) {
    const f32x4* in  = (const f32x4*)d_in[0];
    f32x4*       out = (f32x4*)d_out;
    dim3 block(256, 1, 1);
    dim3 grid((TOTAL4 + CHUNK - 1) / CHUNK, 1, 1);   // 8433 blocks, linear stream
    gather_pairs_kernel<<<grid, block, 0, stream>>>(in, out);
}

// Round 7
// 57.648 us; speedup vs baseline: 1.3663x; 1.3663x over previous
//
#include <hip/hip_runtime.h>

// Output: (224, 2, 257, 600) f32.  plane pl = b*56 + 2*p + s, pl in [0,448)
// src channel per (2*p+s) from triu_indices(8, k=1) pair table.
__device__ __constant__ int c_ch[56] = {
    0,1, 0,2, 0,3, 0,4, 0,5, 0,6, 0,7,
    1,2, 1,3, 1,4, 1,5, 1,6, 1,7,
    2,3, 2,4, 2,5, 2,6, 2,7,
    3,4, 3,5, 3,6, 3,7,
    4,5, 4,6, 4,7,
    5,6, 5,7,
    6,7
};

typedef float f32x4 __attribute__((ext_vector_type(4)));

#define PLANE4 38550   // 257*600/4 float4 per plane (plane = 616800 B, mod 128 = 96)
#define GRIDX  38      // chunks per plane
#define TPP    (GRIDX * 256)   // 9728 threads per plane; 9728*16 B % 128 == 0

// 1-D grid, XCD-batch affinity: w%8 = batch (XCD round-robin), w/8 walks the
// batch's 56 planes x 38 chunks plane-major -> each XCD's read working set is
// one batch's 8 channels (4.9 MB ~ its private L2), triu order keeps ref hot.
__global__ void gather_pairs_kernel(const f32x4* __restrict__ in,
                                    f32x4* __restrict__ out) {
    unsigned w     = blockIdx.x;
    unsigned b     = w & 7u;          // batch == XCD
    unsigned local = w >> 3;          // 0..2127
    unsigned pib   = local / 38u;     // plane in batch, 0..55 (magic-mul)
    unsigned chunk = local - pib * 38u;
    unsigned pl    = b * 56u + pib;
    unsigned ch    = (unsigned)c_ch[pib];   // wave-uniform scalar load

    const f32x4* __restrict__ src = in  + (size_t)((b << 3) + ch) * PLANE4;
    f32x4*       __restrict__ dst = out + (size_t)pl * PLANE4;

    // plane base mod 128 cycles with pl&3: 0,96,64,32. Peel leading float4s
    // so bulk accesses are 128-B line-aligned (loads AND stores).
    int off  = ((pl & 3) * 96) & 127;
    int peel = ((128 - off) & 127) >> 4;   // 0, 2, 4, or 6 float4s

    int t = chunk * 256 + threadIdx.x;     // 0..9727
    if (t < peel) {
        f32x4 v = src[t];
        __builtin_nontemporal_store(v, &dst[t]);
    }

    // 4-deep MLP: all loads issued before any store waits on them.
    int i0 = peel + t;
    int i1 = i0 + TPP;
    int i2 = i1 + TPP;
    int i3 = i2 + TPP;
    bool p3 = i3 < PLANE4;

    f32x4 v0 = src[i0];
    f32x4 v1 = src[i1];
    f32x4 v2 = src[i2];
    f32x4 v3;
    if (p3) v3 = src[i3];

    __builtin_nontemporal_store(v0, &dst[i0]);
    __builtin_nontemporal_store(v1, &dst[i1]);
    __builtin_nontemporal_store(v2, &dst[i2]);
    if (p3) __builtin_nontemporal_store(v3, &dst[i3]);
}

extern "C" void kernel_launch(void* const* d_in, const int* in_sizes, int n_in,
                              void* d_out, int out_size, void* d_ws, size_t ws_size,
                              hipStream_t stream) {
    const f32x4* in  = (const f32x4*)d_in[0];
    f32x4*       out = (f32x4*)d_out;
    dim3 block(256, 1, 1);
    dim3 grid(8 * 56 * GRIDX, 1, 1);   // 17024 blocks, batch-affine
    gather_pairs_kernel<<<grid, block, 0, stream>>>(in, out);
}